// Round 18
// baseline (8282.053 us; speedup 1.0000x reference)
//
#include <hip/hip_runtime.h>
#include <hip/hip_bf16.h>
#include <stdint.h>

#define T_STEPS 4096
#define BATCH 32
#define IDIM 512
#define HDIM 512
#define CDIM 128
#define NSPLIT 8      // blocks per batch (output-dim split)
#define CSLICE 64     // HDIM / NSPLIT
#define QP 68         // padded 64-elem eighth stride (floats): disjoint bank quads

typedef float f32x4 __attribute__((ext_vector_type(4)));
typedef short s16x8 __attribute__((ext_vector_type(8)));
typedef unsigned short u16x4 __attribute__((ext_vector_type(4)));

__device__ __forceinline__ unsigned short f2bf(float f) {
    union { float f; uint32_t u; } v; v.f = f;
    uint32_t r = v.u + 0x7fffu + ((v.u >> 16) & 1u);  // RNE
    return (unsigned short)(r >> 16);
}
__device__ __forceinline__ float bf2f(unsigned short s) {
    union { uint32_t u; float f; } v; v.u = ((uint32_t)s) << 16;
    return v.f;
}

// ---------------------------------------------------------------------------
// 4-deep pipelined tag-spin: keep 4 agent-scope loads of the same word in
// flight; check the oldest, reissue, rotate. Poll period drops from ~1 RT
// (serialized load->waitcnt->check) to ~RT/4, which shrinks both mean
// discovery and the max-straggler over the 512 polled elements.
// Same memory protocol as the proven R10/R16 spin — only overlap changes.
// ---------------------------------------------------------------------------
__device__ __forceinline__ uint32_t spin_tag4(const uint32_t* p, uint32_t exp_tag) {
    uint32_t a0 = __hip_atomic_load(p, __ATOMIC_RELAXED, __HIP_MEMORY_SCOPE_AGENT);
    uint32_t a1 = __hip_atomic_load(p, __ATOMIC_RELAXED, __HIP_MEMORY_SCOPE_AGENT);
    uint32_t a2 = __hip_atomic_load(p, __ATOMIC_RELAXED, __HIP_MEMORY_SCOPE_AGENT);
    uint32_t a3 = __hip_atomic_load(p, __ATOMIC_RELAXED, __HIP_MEMORY_SCOPE_AGENT);
    for (;;) {
        if ((a0 & 1u) == exp_tag) return a0;
        a0 = __hip_atomic_load(p, __ATOMIC_RELAXED, __HIP_MEMORY_SCOPE_AGENT);
        if ((a1 & 1u) == exp_tag) return a1;
        a1 = __hip_atomic_load(p, __ATOMIC_RELAXED, __HIP_MEMORY_SCOPE_AGENT);
        if ((a2 & 1u) == exp_tag) return a2;
        a2 = __hip_atomic_load(p, __ATOMIC_RELAXED, __HIP_MEMORY_SCOPE_AGENT);
        if ((a3 & 1u) == exp_tag) return a3;
        a3 = __hip_atomic_load(p, __ATOMIC_RELAXED, __HIP_MEMORY_SCOPE_AGENT);
    }
}

// ---------------------------------------------------------------------------
// Kernel 0: seed exchange buffers.
// buf0 = h0 with tag 0; buf1 = garbage with tag 1 (0xAA poison has LSB 0 =
// false-ready for gs=1's exp_tag=0, so buf1 MUST be overwritten).
// ---------------------------------------------------------------------------
__global__ void seed_hx(const float* __restrict__ h0, uint32_t* __restrict__ hx) {
    int i = blockIdx.x * 256 + threadIdx.x;
    if (i < BATCH * HDIM) {
        union { float f; uint32_t u; } v; v.f = h0[i];
        hx[i] = v.u & ~1u;                       // buffer 0: h_0, tag 0
        hx[BATCH * HDIM + i] = 0x3f800001u;      // buffer 1: garbage, tag 1
    }
}

// ---------------------------------------------------------------------------
// Kernel 1: A[m][n] = bf16( X[m][:] . Wih[n][:] + bih[n] + bhh[n] )
// ---------------------------------------------------------------------------
__global__ __launch_bounds__(256) void xih_gemm(
    const float* __restrict__ X,    // [M][K] fp32
    const float* __restrict__ Wih,  // [N][K] fp32
    const float* __restrict__ bih,
    const float* __restrict__ bhh,
    unsigned short* __restrict__ A) // [M][N] bf16 bits
{
    __shared__ __align__(16) unsigned short As[128][40];
    __shared__ __align__(16) unsigned short Bs[128][40];

    const int tid  = threadIdx.x;
    const int lane = tid & 63;
    const int wave = tid >> 6;
    const int wr = wave >> 1, wc = wave & 1;
    const int row0 = blockIdx.y * 128;
    const int col0 = blockIdx.x * 128;
    const int l16 = lane & 15, lhi = lane >> 4;

    const int lr = tid >> 3;
    const int kf = tid & 7;

    f32x4 acc[4][4] = {};

    for (int k0 = 0; k0 < IDIM; k0 += 32) {
        #pragma unroll
        for (int rr = 0; rr < 128; rr += 32) {
            int r = lr + rr;
            float4 xv = *(const float4*)&X[(size_t)(row0 + r) * IDIM + k0 + kf * 4];
            float4 wv = *(const float4*)&Wih[(size_t)(col0 + r) * IDIM + k0 + kf * 4];
            u16x4 xq, wq;
            xq.x = f2bf(xv.x); xq.y = f2bf(xv.y); xq.z = f2bf(xv.z); xq.w = f2bf(xv.w);
            wq.x = f2bf(wv.x); wq.y = f2bf(wv.y); wq.z = f2bf(wv.z); wq.w = f2bf(wv.w);
            *(u16x4*)&As[r][kf * 4] = xq;
            *(u16x4*)&Bs[r][kf * 4] = wq;
        }
        __syncthreads();

        s16x8 af[4], bfr[4];
        #pragma unroll
        for (int mi = 0; mi < 4; ++mi)
            af[mi] = *(const s16x8*)&As[wr * 64 + mi * 16 + l16][lhi * 8];
        #pragma unroll
        for (int ni = 0; ni < 4; ++ni)
            bfr[ni] = *(const s16x8*)&Bs[wc * 64 + ni * 16 + l16][lhi * 8];
        #pragma unroll
        for (int mi = 0; mi < 4; ++mi)
            #pragma unroll
            for (int ni = 0; ni < 4; ++ni)
                acc[mi][ni] = __builtin_amdgcn_mfma_f32_16x16x32_bf16(
                    af[mi], bfr[ni], acc[mi][ni], 0, 0, 0);
        __syncthreads();
    }

    #pragma unroll
    for (int ni = 0; ni < 4; ++ni) {
        int col = col0 + wc * 64 + ni * 16 + l16;
        float bias = bih[col] + bhh[col];
        #pragma unroll
        for (int mi = 0; mi < 4; ++mi) {
            int rowb = row0 + wr * 64 + mi * 16 + lhi * 4;
            #pragma unroll
            for (int r = 0; r < 4; ++r)
                A[(size_t)(rowb + r) * HDIM + col] = f2bf(acc[mi][ni][r] + bias);
        }
    }
}

// ---------------------------------------------------------------------------
// Kernel 2: recurrence. 256 blocks (1/CU), NSPLIT=8 -> 64 cols/block.
// Thread: c = tid>>3 (col 0..63), q = tid&7 (K-eighth, 64 elems).
// Sync: mantissa-LSB freshness tag (tag(g)=(g>>1)&1), agent-scope atomics —
// the proven R10/R16 protocol, with the spin upgraded to the 4-deep
// pipelined poll (spin_tag4). Everything else byte-identical to R16.
// ---------------------------------------------------------------------------
__global__ __launch_bounds__(512, 1) void rnn_scan(
    const unsigned short* __restrict__ A,  // [tc][BATCH][HDIM] bf16 bits
    const float* __restrict__ Whh,         // [HDIM][HDIM] row-major
    const float* __restrict__ Wfc,         // [CDIM][HDIM]
    const float* __restrict__ bfc,         // [CDIM]
    uint32_t* __restrict__ hx,             // [2][BATCH][HDIM] tagged fp32 bits
    float* __restrict__ out,               // [BATCH][CDIM]
    float* __restrict__ hfin,              // [BATCH][HDIM] (2nd output)
    int tc, int t0, int do_fc)
{
    __shared__ __align__(16) float hs[2][8 * QP];   // double-buffered staging

    const int tid = threadIdx.x;
    const int b = blockIdx.x >> 3;       // batch
    const int j = blockIdx.x & 7;        // output-slice index
    const int c = tid >> 3;              // local output col 0..63
    const int q = tid & 7;               // k-eighth 0..7
    const int cg = j * CSLICE + c;       // global output col
    const int wq = (tid >> 6) * QP + (tid & 63);  // LDS slot for h[tid]

    // ---- W slice: 16 f32x4 (compiler streams from L2; hidden under sync) ----
    f32x4 w[16];
    {
        const f32x4* wr = (const f32x4*)(Whh + (size_t)cg * HDIM + q * 64);
        #pragma unroll
        for (int i = 0; i < 16; ++i)
            w[i] = wr[i];
    }

    const unsigned short* Ab = A + (size_t)b * HDIM + cg;
    const uint32_t* hin_base = hx + (size_t)b * HDIM + tid;
    uint32_t* hout_base = hx + (size_t)b * HDIM + cg;

    for (int t = 0; t < tc; ++t) {
        const int gs = t0 + t;           // consume h_gs, produce h_{gs+1}
        const uint32_t exp_tag = (uint32_t)((gs >> 1) & 1);

        // additive term (independent load, overlapped with the spin)
        float a_t = bf2f(Ab[(size_t)t * (BATCH * HDIM)]);

        // ---- pipelined spin on my h element (tag = freshness) ----
        const uint32_t* hp = hin_base + (size_t)(gs & 1) * (BATCH * HDIM);
        uint32_t u = spin_tag4(hp, exp_tag);
        union { uint32_t u; float f; } hv_in; hv_in.u = u;
        hs[gs & 1][wq] = hv_in.f;        // tag bit kept: <=2^-23 rel error
        __syncthreads();                 // the ONLY barrier per step

        // ---- partial dot: W x LDS h-eighth ----
        f32x4 acc = {};
        const float* hq = &hs[gs & 1][q * QP];
        #pragma unroll
        for (int i = 0; i < 16; ++i) {
            f32x4 hvv = *(const f32x4*)(hq + i * 4);
            acc += w[i] * hvv;
        }
        float v = acc.x + acc.y + acc.z + acc.w;
        v += __shfl_xor(v, 1);
        v += __shfl_xor(v, 2);
        v += __shfl_xor(v, 4);
        v = fmaxf(v + a_t, 0.f);

        // ---- publish h_{gs+1} with tag(gs+1) in LSB ----
        if (q == 0) {
            union { float f; uint32_t u; } pv; pv.f = v;
            pv.u = (pv.u & ~1u) | (uint32_t)(((gs + 1) >> 1) & 1);
            uint32_t* ho = hout_base + (size_t)((gs + 1) & 1) * (BATCH * HDIM);
            __hip_atomic_store(ho, pv.u, __ATOMIC_RELAXED,
                               __HIP_MEMORY_SCOPE_AGENT);
            if (do_fc && t == tc - 1)
                hfin[b * HDIM + cg] = v;   // plain store, flushed at kernel end
        }
        // no trailing barrier: LDS double-buffered, spin handles ordering
    }

    // ---- fused FC on final h (block j==0 of each batch) ----
    if (do_fc && j == 0) {
        const int target = t0 + tc;
        const uint32_t exp_tag = (uint32_t)((target >> 1) & 1);
        const uint32_t* hp = hin_base + (size_t)(target & 1) * (BATCH * HDIM);
        uint32_t u = spin_tag4(hp, exp_tag);
        union { uint32_t u; float f; } hv_in; hv_in.u = u;
        hs[target & 1][wq] = hv_in.f;
        __syncthreads();

        // out[b][c2] = bfc[c2] + sum_k Wfc[c2][k] * h[k]; c2 = tid>>2, q2 = tid&3
        const int c2 = tid >> 2;
        const int q2 = tid & 3;
        float facc = 0.f;
        const float* wf = Wfc + (size_t)c2 * HDIM + q2 * 128;
        const float* hb2 = hs[target & 1];
        #pragma unroll
        for (int i = 0; i < 32; ++i) {
            int e = q2 * 128 + i * 4;                       // logical h element
            f32x4 hvv = *(const f32x4*)(hb2 + (e >> 6) * QP + (e & 63));
            f32x4 wv = *(const f32x4*)(wf + i * 4);
            f32x4 p = wv * hvv;
            facc += p.x + p.y + p.z + p.w;
        }
        facc += __shfl_xor(facc, 1);
        facc += __shfl_xor(facc, 2);
        if (q2 == 0)
            out[b * CDIM + c2] = facc + bfc[c2];
    }
}

// ---------------------------------------------------------------------------
extern "C" void kernel_launch(void* const* d_in, const int* in_sizes, int n_in,
                              void* d_out, int out_size, void* d_ws, size_t ws_size,
                              hipStream_t stream) {
    const float* x   = (const float*)d_in[0];  // [T][B][I]
    const float* h0  = (const float*)d_in[1];  // [B][H]
    const float* Wih = (const float*)d_in[2];  // [H][I]
    const float* bih = (const float*)d_in[3];  // [H]
    const float* Whh = (const float*)d_in[4];  // [H][H]
    const float* bhh = (const float*)d_in[5];  // [H]
    const float* Wfc = (const float*)d_in[6];  // [C][H]
    const float* bfc = (const float*)d_in[7];  // [C]

    float* out  = (float*)d_out;               // [B][C]
    float* hfin = out + BATCH * CDIM;          // [B][H]

    // d_ws layout: [hx: 2*B*H u32][Abuf: rest]
    uint32_t* hx = (uint32_t*)d_ws;
    const size_t hx_bytes = (size_t)2 * BATCH * HDIM * sizeof(uint32_t);  // 128 KB
    unsigned short* Abuf = (unsigned short*)((char*)d_ws + hx_bytes);

    const size_t per_t = (size_t)BATCH * HDIM * sizeof(unsigned short);   // 32 KB
    size_t avail = ws_size > hx_bytes ? ws_size - hx_bytes : 0;
    long long tcl = (long long)(avail / per_t);
    if (tcl > T_STEPS) tcl = T_STEPS;
    int TC = (int)(tcl & ~3LL);
    if (TC < 4) TC = 4;

    seed_hx<<<(BATCH * HDIM + 255) / 256, 256, 0, stream>>>(h0, hx);

    for (int t0 = 0; t0 < T_STEPS; t0 += TC) {
        int tc = T_STEPS - t0 < TC ? T_STEPS - t0 : TC;
        xih_gemm<<<dim3(4, tc * BATCH / 128), 256, 0, stream>>>(
            x + (size_t)t0 * BATCH * IDIM, Wih, bih, bhh, Abuf);
        int do_fc = (t0 + tc >= T_STEPS) ? 1 : 0;
        rnn_scan<<<BATCH * NSPLIT, 512, 0, stream>>>(
            Abuf, Whh, Wfc, bfc, hx, out, hfin, tc, t0, do_fc);
    }
}

// Round 19
// 7846.497 us; speedup vs baseline: 1.0555x; 1.0555x over previous
//
#include <hip/hip_runtime.h>
#include <hip/hip_bf16.h>
#include <stdint.h>

#define T_STEPS 4096
#define BATCH 32
#define IDIM 512
#define HDIM 512
#define CDIM 128
#define NSPLIT 8      // blocks per batch (output-dim split)
#define CSLICE 64     // HDIM / NSPLIT
#define QP 68         // padded 64-elem eighth stride (floats): disjoint bank quads

typedef float f32x4 __attribute__((ext_vector_type(4)));
typedef short s16x8 __attribute__((ext_vector_type(8)));
typedef unsigned short u16x4 __attribute__((ext_vector_type(4)));

__device__ __forceinline__ unsigned short f2bf(float f) {
    union { float f; uint32_t u; } v; v.f = f;
    uint32_t r = v.u + 0x7fffu + ((v.u >> 16) & 1u);  // RNE
    return (unsigned short)(r >> 16);
}
__device__ __forceinline__ float bf2f(unsigned short s) {
    union { uint32_t u; float f; } v; v.u = ((uint32_t)s) << 16;
    return v.f;
}

// ---------------------------------------------------------------------------
// Kernel 0: seed exchange buffers.
// buf0 = h0 with tag 0; buf1 = garbage with tag 1 (0xAA poison has LSB 0 =
// false-ready for gs=1's exp_tag=0, so buf1 MUST be overwritten).
// ---------------------------------------------------------------------------
__global__ void seed_hx(const float* __restrict__ h0, uint32_t* __restrict__ hx) {
    int i = blockIdx.x * 256 + threadIdx.x;
    if (i < BATCH * HDIM) {
        union { float f; uint32_t u; } v; v.f = h0[i];
        hx[i] = v.u & ~1u;                       // buffer 0: h_0, tag 0
        hx[BATCH * HDIM + i] = 0x3f800001u;      // buffer 1: garbage, tag 1
    }
}

// ---------------------------------------------------------------------------
// Kernel 1: A[m][n] = bf16( X[m][:] . Wih[n][:] + bih[n] + bhh[n] )
// ---------------------------------------------------------------------------
__global__ __launch_bounds__(256) void xih_gemm(
    const float* __restrict__ X,    // [M][K] fp32
    const float* __restrict__ Wih,  // [N][K] fp32
    const float* __restrict__ bih,
    const float* __restrict__ bhh,
    unsigned short* __restrict__ A) // [M][N] bf16 bits
{
    __shared__ __align__(16) unsigned short As[128][40];
    __shared__ __align__(16) unsigned short Bs[128][40];

    const int tid  = threadIdx.x;
    const int lane = tid & 63;
    const int wave = tid >> 6;
    const int wr = wave >> 1, wc = wave & 1;
    const int row0 = blockIdx.y * 128;
    const int col0 = blockIdx.x * 128;
    const int l16 = lane & 15, lhi = lane >> 4;

    const int lr = tid >> 3;
    const int kf = tid & 7;

    f32x4 acc[4][4] = {};

    for (int k0 = 0; k0 < IDIM; k0 += 32) {
        #pragma unroll
        for (int rr = 0; rr < 128; rr += 32) {
            int r = lr + rr;
            float4 xv = *(const float4*)&X[(size_t)(row0 + r) * IDIM + k0 + kf * 4];
            float4 wv = *(const float4*)&Wih[(size_t)(col0 + r) * IDIM + k0 + kf * 4];
            u16x4 xq, wq;
            xq.x = f2bf(xv.x); xq.y = f2bf(xv.y); xq.z = f2bf(xv.z); xq.w = f2bf(xv.w);
            wq.x = f2bf(wv.x); wq.y = f2bf(wv.y); wq.z = f2bf(wv.z); wq.w = f2bf(wv.w);
            *(u16x4*)&As[r][kf * 4] = xq;
            *(u16x4*)&Bs[r][kf * 4] = wq;
        }
        __syncthreads();

        s16x8 af[4], bfr[4];
        #pragma unroll
        for (int mi = 0; mi < 4; ++mi)
            af[mi] = *(const s16x8*)&As[wr * 64 + mi * 16 + l16][lhi * 8];
        #pragma unroll
        for (int ni = 0; ni < 4; ++ni)
            bfr[ni] = *(const s16x8*)&Bs[wc * 64 + ni * 16 + l16][lhi * 8];
        #pragma unroll
        for (int mi = 0; mi < 4; ++mi)
            #pragma unroll
            for (int ni = 0; ni < 4; ++ni)
                acc[mi][ni] = __builtin_amdgcn_mfma_f32_16x16x32_bf16(
                    af[mi], bfr[ni], acc[mi][ni], 0, 0, 0);
        __syncthreads();
    }

    #pragma unroll
    for (int ni = 0; ni < 4; ++ni) {
        int col = col0 + wc * 64 + ni * 16 + l16;
        float bias = bih[col] + bhh[col];
        #pragma unroll
        for (int mi = 0; mi < 4; ++mi) {
            int rowb = row0 + wr * 64 + mi * 16 + lhi * 4;
            #pragma unroll
            for (int r = 0; r < 4; ++r)
                A[(size_t)(rowb + r) * HDIM + col] = f2bf(acc[mi][ni][r] + bias);
        }
    }
}

// ---------------------------------------------------------------------------
// Kernel 2: recurrence. 256 blocks (1/CU), NSPLIT=8 -> 64 cols/block.
// Thread: c = tid>>3 (col 0..63), q = tid&7 (K-eighth, 64 elems).
// Sync: mantissa-LSB freshness tag (tag(g)=(g>>1)&1), spin on own element,
// agent-scope atomics. Measured floor: ~1.86us/step, store-visibility +
// straggler-max bound (R10/R16/R18 convergence; L2-local transport hangs).
// ---------------------------------------------------------------------------
__global__ __launch_bounds__(512, 1) void rnn_scan(
    const unsigned short* __restrict__ A,  // [tc][BATCH][HDIM] bf16 bits
    const float* __restrict__ Whh,         // [HDIM][HDIM] row-major
    const float* __restrict__ Wfc,         // [CDIM][HDIM]
    const float* __restrict__ bfc,         // [CDIM]
    uint32_t* __restrict__ hx,             // [2][BATCH][HDIM] tagged fp32 bits
    float* __restrict__ out,               // [BATCH][CDIM]
    float* __restrict__ hfin,              // [BATCH][HDIM] (2nd output)
    int tc, int t0, int do_fc)
{
    __shared__ __align__(16) float hs[2][8 * QP];   // double-buffered staging

    const int tid = threadIdx.x;
    const int b = blockIdx.x >> 3;       // batch
    const int j = blockIdx.x & 7;        // output-slice index
    const int c = tid >> 3;              // local output col 0..63
    const int q = tid & 7;               // k-eighth 0..7
    const int cg = j * CSLICE + c;       // global output col
    const int wq = (tid >> 6) * QP + (tid & 63);  // LDS slot for h[tid]

    // ---- W slice: 16 f32x4 (streams from L2; fully hidden under sync) ----
    f32x4 w[16];
    {
        const volatile f32x4* wr =
            (const volatile f32x4*)(Whh + (size_t)cg * HDIM + q * 64);
        #pragma unroll
        for (int i = 0; i < 16; ++i)
            w[i] = wr[i];
    }

    const unsigned short* Ab = A + (size_t)b * HDIM + cg;
    const uint32_t* hin_base = hx + (size_t)b * HDIM + tid;
    uint32_t* hout_base = hx + (size_t)b * HDIM + cg;

    for (int t = 0; t < tc; ++t) {
        const int gs = t0 + t;           // consume h_gs, produce h_{gs+1}
        const uint32_t exp_tag = (uint32_t)((gs >> 1) & 1);

        // additive term (independent load, overlapped with the spin)
        float a_t = bf2f(Ab[(size_t)t * (BATCH * HDIM)]);

        // ---- spin directly on my h element (tag = freshness) ----
        const uint32_t* hp = hin_base + (size_t)(gs & 1) * (BATCH * HDIM);
        uint32_t u;
        while (((u = __hip_atomic_load(hp, __ATOMIC_RELAXED,
                                       __HIP_MEMORY_SCOPE_AGENT)) & 1u) != exp_tag) {}
        union { uint32_t u; float f; } hv_in; hv_in.u = u;
        hs[gs & 1][wq] = hv_in.f;        // tag bit kept: <=2^-23 rel error
        __syncthreads();                 // the ONLY barrier per step

        // ---- partial dot: W x LDS h-eighth ----
        f32x4 acc = {};
        const float* hq = &hs[gs & 1][q * QP];
        #pragma unroll
        for (int i = 0; i < 16; ++i) {
            f32x4 hvv = *(const f32x4*)(hq + i * 4);
            acc += w[i] * hvv;
        }
        float v = acc.x + acc.y + acc.z + acc.w;
        v += __shfl_xor(v, 1);
        v += __shfl_xor(v, 2);
        v += __shfl_xor(v, 4);
        v = fmaxf(v + a_t, 0.f);

        // ---- publish h_{gs+1} with tag(gs+1) in LSB ----
        if (q == 0) {
            union { float f; uint32_t u; } pv; pv.f = v;
            pv.u = (pv.u & ~1u) | (uint32_t)(((gs + 1) >> 1) & 1);
            uint32_t* ho = hout_base + (size_t)((gs + 1) & 1) * (BATCH * HDIM);
            __hip_atomic_store(ho, pv.u, __ATOMIC_RELAXED,
                               __HIP_MEMORY_SCOPE_AGENT);
            if (do_fc && t == tc - 1)
                hfin[b * HDIM + cg] = v;   // plain store, flushed at kernel end
        }
        // no trailing barrier: LDS double-buffered, spin handles ordering
    }

    // ---- fused FC on final h (block j==0 of each batch) ----
    if (do_fc && j == 0) {
        const int target = t0 + tc;
        const uint32_t exp_tag = (uint32_t)((target >> 1) & 1);
        const uint32_t* hp = hin_base + (size_t)(target & 1) * (BATCH * HDIM);
        uint32_t u;
        while (((u = __hip_atomic_load(hp, __ATOMIC_RELAXED,
                                       __HIP_MEMORY_SCOPE_AGENT)) & 1u) != exp_tag) {}
        union { uint32_t u; float f; } hv_in; hv_in.u = u;
        hs[target & 1][wq] = hv_in.f;
        __syncthreads();

        // out[b][c2] = bfc[c2] + sum_k Wfc[c2][k] * h[k]; c2 = tid>>2, q2 = tid&3
        const int c2 = tid >> 2;
        const int q2 = tid & 3;
        float facc = 0.f;
        const float* wf = Wfc + (size_t)c2 * HDIM + q2 * 128;
        const float* hb2 = hs[target & 1];
        #pragma unroll
        for (int i = 0; i < 32; ++i) {
            int e = q2 * 128 + i * 4;                       // logical h element
            f32x4 hvv = *(const f32x4*)(hb2 + (e >> 6) * QP + (e & 63));
            f32x4 wv = *(const f32x4*)(wf + i * 4);
            f32x4 p = wv * hvv;
            facc += p.x + p.y + p.z + p.w;
        }
        facc += __shfl_xor(facc, 1);
        facc += __shfl_xor(facc, 2);
        if (q2 == 0)
            out[b * CDIM + c2] = facc + bfc[c2];
    }
}

// ---------------------------------------------------------------------------
extern "C" void kernel_launch(void* const* d_in, const int* in_sizes, int n_in,
                              void* d_out, int out_size, void* d_ws, size_t ws_size,
                              hipStream_t stream) {
    const float* x   = (const float*)d_in[0];  // [T][B][I]
    const float* h0  = (const float*)d_in[1];  // [B][H]
    const float* Wih = (const float*)d_in[2];  // [H][I]
    const float* bih = (const float*)d_in[3];  // [H]
    const float* Whh = (const float*)d_in[4];  // [H][H]
    const float* bhh = (const float*)d_in[5];  // [H]
    const float* Wfc = (const float*)d_in[6];  // [C][H]
    const float* bfc = (const float*)d_in[7];  // [C]

    float* out  = (float*)d_out;               // [B][C]
    float* hfin = out + BATCH * CDIM;          // [B][H]

    // d_ws layout: [hx: 2*B*H u32][Abuf: rest]
    uint32_t* hx = (uint32_t*)d_ws;
    const size_t hx_bytes = (size_t)2 * BATCH * HDIM * sizeof(uint32_t);  // 128 KB
    unsigned short* Abuf = (unsigned short*)((char*)d_ws + hx_bytes);

    const size_t per_t = (size_t)BATCH * HDIM * sizeof(unsigned short);   // 32 KB
    size_t avail = ws_size > hx_bytes ? ws_size - hx_bytes : 0;
    long long tcl = (long long)(avail / per_t);
    if (tcl > T_STEPS) tcl = T_STEPS;
    int TC = (int)(tcl & ~3LL);
    if (TC < 4) TC = 4;

    seed_hx<<<(BATCH * HDIM + 255) / 256, 256, 0, stream>>>(h0, hx);

    for (int t0 = 0; t0 < T_STEPS; t0 += TC) {
        int tc = T_STEPS - t0 < TC ? T_STEPS - t0 : TC;
        xih_gemm<<<dim3(4, tc * BATCH / 128), 256, 0, stream>>>(
            x + (size_t)t0 * BATCH * IDIM, Wih, bih, bhh, Abuf);
        int do_fc = (t0 + tc >= T_STEPS) ? 1 : 0;
        rnn_scan<<<BATCH * NSPLIT, 512, 0, stream>>>(
            Abuf, Whh, Wfc, bfc, hx, out, hfin, tc, t0, do_fc);
    }
}